// Round 7
// baseline (471.488 us; speedup 1.0000x reference)
//
#include <hip/hip_runtime.h>
#include <hip/hip_bf16.h>
#include <stdint.h>

// Problem constants: B=2, H=16, S=2048, D=64, fp32 in/out.
#define BB 2
#define HH 16
#define SS 2048
#define DD 64
constexpr int BH = BB * HH;
constexpr int NT = SS / 64;    // 32 K-tiles

typedef __bf16 bf16_t;
typedef bf16_t bf16x8 __attribute__((ext_vector_type(8)));
typedef float f32x4 __attribute__((ext_vector_type(4)));

// Workspace (bf16): Khi[BH][SS][DD] | Klo[BH][SS][DD] | Vt[BH][DD][SS] | flags[BH*NT] u32
constexpr size_t WS_K     = (size_t)BH * SS * DD;     // 4,194,304 elems
constexpr size_t WS_NEED  = WS_K * 2 * 3;             // 25,165,824 bytes
constexpr size_t WS_FUSED = WS_NEED + (size_t)BH * NT * 4;  // + 4KB flags

__device__ __forceinline__ bf16_t f2bf(float f) {
    uint32_t u = __float_as_uint(f);
    u += 0x7FFFu + ((u >> 16) & 1u);
    return __builtin_bit_cast(bf16_t, (uint16_t)(u >> 16));
}
__device__ __forceinline__ float bf2f(bf16_t h) {
    uint32_t u = ((uint32_t)__builtin_bit_cast(uint16_t, h)) << 16;
    return __uint_as_float(u);
}
struct BfPair { bf16_t hi, lo; };
__device__ __forceinline__ BfPair split_bf(float f) {
    BfPair p;
    p.hi = f2bf(f);
    p.lo = f2bf(f - bf2f(p.hi));
    return p;
}
__device__ __forceinline__ uint32_t pack2f(float a, float b) {
    uint32_t ua = __float_as_uint(a), ub = __float_as_uint(b);
    ua += 0x7FFFu + ((ua >> 16) & 1u);
    ub += 0x7FFFu + ((ub >> 16) & 1u);
    return (ua >> 16) | (ub & 0xFFFF0000u);
}

// ================= Fused single-launch kernel (manual per-bh barrier) =================
// Phase A: block (bh,qt) converts K/V tile kt=qt of its bh into workspace, then
// release-stores flags[bh*NT+qt]=1. Blocks sharing bh acquire-spin on all 32 flags
// (poison 0xAAAAAAAA != 1 => re-poison per replay resets the barrier). All 1024
// blocks are co-resident (4/CU by LDS; __launch_bounds__(256,4) caps VGPRs), so
// the barrier cannot starve; a bounded spin guarantees no hang regardless.
__global__ __launch_bounds__(256, 4)
void fattn_fused(const float* __restrict__ Qg, const float* __restrict__ Kg,
                 const float* __restrict__ Vg, const float* __restrict__ Mg,
                 const float* __restrict__ Sg, float* __restrict__ Og,
                 bf16_t* __restrict__ Khi, bf16_t* __restrict__ Klo,
                 bf16_t* __restrict__ Vtw, uint32_t* __restrict__ flags)
{
    __shared__ __align__(16) bf16_t Kh_lds[64][72];
    __shared__ __align__(16) bf16_t Kl_lds[64][72];
    __shared__ __align__(16) bf16_t Vt_lds[DD][72];
    __shared__ __align__(16) bf16_t Pt_lds[4][16][72];   // phase A overlays as T[64][72]

    const int bh   = blockIdx.x % BH;      // bh-minor => XCD spread
    const int qt   = blockIdx.x / BH;      // 0..31
    const int b    = bh / HH;
    const int tid  = threadIdx.x;
    const int wave = tid >> 6;
    const int lane = tid & 63;
    const int l16  = lane & 15;
    const int quad = lane >> 4;

    const float sc = Sg[b] * 1.44269504088896340736f;
    const size_t base = (size_t)bh * SS * DD;
    const int q0 = qt * 64 + wave * 16;

    // ---------- Phase A: convert own tile (keys [qt*64, qt*64+64)) ----------
    {
        const int k0 = qt * 64;
        {   // K hi/lo: thread handles row tid>>2, 16 cols at (tid&3)*16
            const int row = tid >> 2, c16 = (tid & 3) * 16;
            const size_t off = ((size_t)bh * SS + k0 + row) * DD + c16;
            const float* kp = Kg + off;
            bf16x8 h0, h1, l0, l1;
#pragma unroll
            for (int j = 0; j < 8; ++j) {
                BfPair p = split_bf(kp[j]);
                h0[j] = p.hi; l0[j] = p.lo;
            }
#pragma unroll
            for (int j = 0; j < 8; ++j) {
                BfPair p = split_bf(kp[8 + j]);
                h1[j] = p.hi; l1[j] = p.lo;
            }
            *(bf16x8*)(Khi + off)     = h0;
            *(bf16x8*)(Khi + off + 8) = h1;
            *(bf16x8*)(Klo + off)     = l0;
            *(bf16x8*)(Klo + off + 8) = l1;
        }
        {   // V transpose + mask fold via LDS (overlay Pt_lds as T[64][72])
            bf16_t (*T)[72] = (bf16_t(*)[72])&Pt_lds[0][0][0];
            const int kr = tid >> 4, c4 = (tid & 15) * 4;
#pragma unroll
            for (int i = 0; i < 4; ++i) {
                const int key = kr + i * 16;
                const float m = Mg[(size_t)b * SS + k0 + key];
                float4 v = *(const float4*)(Vg + ((size_t)bh * SS + k0 + key) * DD + c4);
                T[c4 + 0][key] = f2bf(v.x * m);
                T[c4 + 1][key] = f2bf(v.y * m);
                T[c4 + 2][key] = f2bf(v.z * m);
                T[c4 + 3][key] = f2bf(v.w * m);
            }
            __syncthreads();
            const int d = tid >> 2, kc = (tid & 3) * 16;
            bf16_t* dst = Vtw + ((size_t)bh * DD + d) * SS + k0 + kc;
            *(bf16x8*)(dst)     = *(const bf16x8*)&T[d][kc];
            *(bf16x8*)(dst + 8) = *(const bf16x8*)&T[d][kc + 8];
        }
    }

    // ---------- Q fragments (B-operand layout), hi/lo split of (q * sc) ----------
    bf16x8 qhi[2], qlo[2];
    {
        const float* qp = Qg + base + (size_t)(q0 + l16) * DD + quad * 8;
#pragma unroll
        for (int kc = 0; kc < 2; ++kc) {
            float4 a  = *(const float4*)(qp + kc * 32);
            float4 b4 = *(const float4*)(qp + kc * 32 + 4);
            bf16x8 fh, fl;
            BfPair p;
            p = split_bf(a.x * sc);  fh[0] = p.hi; fl[0] = p.lo;
            p = split_bf(a.y * sc);  fh[1] = p.hi; fl[1] = p.lo;
            p = split_bf(a.z * sc);  fh[2] = p.hi; fl[2] = p.lo;
            p = split_bf(a.w * sc);  fh[3] = p.hi; fl[3] = p.lo;
            p = split_bf(b4.x * sc); fh[4] = p.hi; fl[4] = p.lo;
            p = split_bf(b4.y * sc); fh[5] = p.hi; fl[5] = p.lo;
            p = split_bf(b4.z * sc); fh[6] = p.hi; fl[6] = p.lo;
            p = split_bf(b4.w * sc); fh[7] = p.hi; fl[7] = p.lo;
            qhi[kc] = fh; qlo[kc] = fl;
        }
    }

    // ---------- Per-bh barrier: arrive (release), wait (acquire) ----------
    __syncthreads();           // all waves' phase-A stores drained (vmcnt0 at barrier)
    __threadfence();           // agent-scope visibility (cross-XCD L2)
    if (tid == 0)
        __hip_atomic_store(&flags[bh * NT + qt], 1u, __ATOMIC_RELEASE, __HIP_MEMORY_SCOPE_AGENT);
    if (tid < NT) {
        const uint32_t* f = &flags[bh * NT + tid];
        int guard = 0;
        while (__hip_atomic_load(f, __ATOMIC_ACQUIRE, __HIP_MEMORY_SCOPE_AGENT) != 1u) {
            if (++guard > (1 << 19)) break;   // failsafe: wrong answer, never a hang
            __builtin_amdgcn_s_sleep(2);
        }
    }
    __syncthreads();
    __threadfence();

    // ---------- Phase B: attention over all tiles of this bh (R5-validated loop) ----------
    f32x4 Ot[4];
#pragma unroll
    for (int mt = 0; mt < 4; ++mt) Ot[mt] = f32x4{0.f, 0.f, 0.f, 0.f};
    float m_run = -1e30f, l_run = 0.0f;

    const int srow = tid >> 2;
    const int scol = (tid & 3) * 16;
    const bf16_t* khp = Khi + ((size_t)bh * SS + srow) * DD + scol;
    const bf16_t* klp = Klo + ((size_t)bh * SS + srow) * DD + scol;
    const bf16_t* vsp = Vtw + ((size_t)bh * DD + srow) * SS + scol;

    bf16x8 rkh0, rkh1, rkl0, rkl1, rv0, rv1;
    rkh0 = *(const bf16x8*)(khp);     rkh1 = *(const bf16x8*)(khp + 8);
    rkl0 = *(const bf16x8*)(klp);     rkl1 = *(const bf16x8*)(klp + 8);
    rv0  = *(const bf16x8*)(vsp);     rv1  = *(const bf16x8*)(vsp + 8);

    for (int kt = 0; kt < NT; ++kt) {
        __syncthreads();
        *(bf16x8*)&Kh_lds[srow][scol]     = rkh0;
        *(bf16x8*)&Kh_lds[srow][scol + 8] = rkh1;
        *(bf16x8*)&Kl_lds[srow][scol]     = rkl0;
        *(bf16x8*)&Kl_lds[srow][scol + 8] = rkl1;
        *(bf16x8*)&Vt_lds[srow][scol]     = rv0;
        *(bf16x8*)&Vt_lds[srow][scol + 8] = rv1;
        __syncthreads();

        if (kt + 1 < NT) {
            const bf16_t* kh = khp + (size_t)(kt + 1) * 64 * DD;
            const bf16_t* kl = klp + (size_t)(kt + 1) * 64 * DD;
            const bf16_t* vs = vsp + (kt + 1) * 64;
            rkh0 = *(const bf16x8*)(kh);  rkh1 = *(const bf16x8*)(kh + 8);
            rkl0 = *(const bf16x8*)(kl);  rkl1 = *(const bf16x8*)(kl + 8);
            rv0  = *(const bf16x8*)(vs);  rv1  = *(const bf16x8*)(vs + 8);
        }

        // S^T = K Q^T
        f32x4 Sfr[4];
#pragma unroll
        for (int mt = 0; mt < 4; ++mt) {
            f32x4 acc = f32x4{0.f, 0.f, 0.f, 0.f};
#pragma unroll
            for (int kc = 0; kc < 2; ++kc) {
                bf16x8 kh = *(const bf16x8*)&Kh_lds[mt * 16 + l16][kc * 32 + quad * 8];
                bf16x8 kl = *(const bf16x8*)&Kl_lds[mt * 16 + l16][kc * 32 + quad * 8];
                acc = __builtin_amdgcn_mfma_f32_16x16x32_bf16(kh, qhi[kc], acc, 0, 0, 0);
                acc = __builtin_amdgcn_mfma_f32_16x16x32_bf16(kh, qlo[kc], acc, 0, 0, 0);
                acc = __builtin_amdgcn_mfma_f32_16x16x32_bf16(kl, qhi[kc], acc, 0, 0, 0);
            }
            Sfr[mt] = acc;
        }

        // Online softmax (16 in-lane values, q = l16); wave-uniform rescale skip (exact)
        float mx = Sfr[0][0];
#pragma unroll
        for (int mt = 0; mt < 4; ++mt)
#pragma unroll
            for (int r = 0; r < 4; ++r) mx = fmaxf(mx, Sfr[mt][r]);
        mx = fmaxf(mx, __shfl_xor(mx, 16));
        mx = fmaxf(mx, __shfl_xor(mx, 32));

        if (__any(mx > m_run)) {
            const float mnew  = fmaxf(m_run, mx);
            const float alpha = exp2f(m_run - mnew);
            m_run = mnew;
            l_run *= alpha;
#pragma unroll
            for (int mt = 0; mt < 4; ++mt) Ot[mt] *= alpha;
        }

        float ps[4][4];
        float rs = 0.0f;
#pragma unroll
        for (int mt = 0; mt < 4; ++mt)
#pragma unroll
            for (int r = 0; r < 4; ++r) {
                ps[mt][r] = exp2f(Sfr[mt][r] - m_run);
                rs += ps[mt][r];
            }
        rs += __shfl_xor(rs, 16);
        rs += __shfl_xor(rs, 32);
        l_run += rs;

        // P^T -> LDS (4x ds_write_b64)
#pragma unroll
        for (int mt = 0; mt < 4; ++mt) {
            uint2 w = make_uint2(pack2f(ps[mt][0], ps[mt][1]),
                                 pack2f(ps[mt][2], ps[mt][3]));
            *(uint2*)&Pt_lds[wave][l16][mt * 16 + quad * 4] = w;
        }

        // O^T += V^T P^T
#pragma unroll
        for (int kc = 0; kc < 2; ++kc) {
            bf16x8 pf = *(const bf16x8*)&Pt_lds[wave][l16][kc * 32 + quad * 8];
#pragma unroll
            for (int mt = 0; mt < 4; ++mt) {
                bf16x8 vf = *(const bf16x8*)&Vt_lds[mt * 16 + l16][kc * 32 + quad * 8];
                Ot[mt] = __builtin_amdgcn_mfma_f32_16x16x32_bf16(vf, pf, Ot[mt], 0, 0, 0);
            }
        }
    }

    // Epilogue: O[q][d] = O^T[d][q] / l
    const float inv = 1.0f / l_run;
    float* op = Og + base + (size_t)(q0 + l16) * DD + quad * 4;
#pragma unroll
    for (int mt = 0; mt < 4; ++mt) {
#pragma unroll
        for (int r = 0; r < 4; ++r)
            op[mt * 16 + r] = Ot[mt][r] * inv;
    }
}

// ================= Fallback path A: R5 two-kernel =================
__global__ __launch_bounds__(256)
void conv_kv(const float* __restrict__ K, const float* __restrict__ V,
             const float* __restrict__ Mg,
             bf16_t* __restrict__ Khi, bf16_t* __restrict__ Klo, bf16_t* __restrict__ Vt) {
    __shared__ __align__(16) bf16_t T[DD][72];
    const int bh = blockIdx.x % BH;
    const int kb = blockIdx.x / BH;
    const int b  = bh / HH;
    const int k0 = kb * 64;
    const int tid = threadIdx.x;
    {
        const int row = tid >> 2, c16 = (tid & 3) * 16;
        const size_t off = ((size_t)bh * SS + k0 + row) * DD + c16;
        const float* kp = K + off;
        bf16x8 h0, h1, l0, l1;
#pragma unroll
        for (int j = 0; j < 8; ++j) {
            BfPair p = split_bf(kp[j]);
            h0[j] = p.hi; l0[j] = p.lo;
        }
#pragma unroll
        for (int j = 0; j < 8; ++j) {
            BfPair p = split_bf(kp[8 + j]);
            h1[j] = p.hi; l1[j] = p.lo;
        }
        *(bf16x8*)(Khi + off)     = h0;
        *(bf16x8*)(Khi + off + 8) = h1;
        *(bf16x8*)(Klo + off)     = l0;
        *(bf16x8*)(Klo + off + 8) = l1;
    }
    {
        const int kr = tid >> 4, c4 = (tid & 15) * 4;
#pragma unroll
        for (int i = 0; i < 4; ++i) {
            const int key = kr + i * 16;
            const float m = Mg[(size_t)b * SS + k0 + key];
            float4 v = *(const float4*)(V + ((size_t)bh * SS + k0 + key) * DD + c4);
            T[c4 + 0][key] = f2bf(v.x * m);
            T[c4 + 1][key] = f2bf(v.y * m);
            T[c4 + 2][key] = f2bf(v.z * m);
            T[c4 + 3][key] = f2bf(v.w * m);
        }
        __syncthreads();
        const int d = tid >> 2, kc = (tid & 3) * 16;
        bf16_t* dst = Vt + ((size_t)bh * DD + d) * SS + k0 + kc;
        *(bf16x8*)(dst)     = *(const bf16x8*)&T[d][kc];
        *(bf16x8*)(dst + 8) = *(const bf16x8*)&T[d][kc + 8];
    }
}

__global__ __launch_bounds__(256)
void fattn3(const float* __restrict__ Qg, const bf16_t* __restrict__ Khi,
            const bf16_t* __restrict__ Klo, const bf16_t* __restrict__ Vtw,
            const float* __restrict__ Sg, float* __restrict__ Og)
{
    __shared__ __align__(16) bf16_t Kh_lds[64][72];
    __shared__ __align__(16) bf16_t Kl_lds[64][72];
    __shared__ __align__(16) bf16_t Vt_lds[DD][72];
    __shared__ __align__(16) bf16_t Pt_lds[4][16][72];

    const int bh   = blockIdx.x % BH;
    const int qt   = blockIdx.x / BH;
    const int b    = bh / HH;
    const int tid  = threadIdx.x;
    const int wave = tid >> 6;
    const int lane = tid & 63;
    const int l16  = lane & 15;
    const int quad = lane >> 4;

    const float sc = Sg[b] * 1.44269504088896340736f;
    const size_t base = (size_t)bh * SS * DD;
    const int q0 = qt * 64 + wave * 16;

    bf16x8 qhi[2], qlo[2];
    {
        const float* qp = Qg + base + (size_t)(q0 + l16) * DD + quad * 8;
#pragma unroll
        for (int kc = 0; kc < 2; ++kc) {
            float4 a  = *(const float4*)(qp + kc * 32);
            float4 b4 = *(const float4*)(qp + kc * 32 + 4);
            bf16x8 fh, fl;
            BfPair p;
            p = split_bf(a.x * sc);  fh[0] = p.hi; fl[0] = p.lo;
            p = split_bf(a.y * sc);  fh[1] = p.hi; fl[1] = p.lo;
            p = split_bf(a.z * sc);  fh[2] = p.hi; fl[2] = p.lo;
            p = split_bf(a.w * sc);  fh[3] = p.hi; fl[3] = p.lo;
            p = split_bf(b4.x * sc); fh[4] = p.hi; fl[4] = p.lo;
            p = split_bf(b4.y * sc); fh[5] = p.hi; fl[5] = p.lo;
            p = split_bf(b4.z * sc); fh[6] = p.hi; fl[6] = p.lo;
            p = split_bf(b4.w * sc); fh[7] = p.hi; fl[7] = p.lo;
            qhi[kc] = fh; qlo[kc] = fl;
        }
    }

    f32x4 Ot[4];
#pragma unroll
    for (int mt = 0; mt < 4; ++mt) Ot[mt] = f32x4{0.f, 0.f, 0.f, 0.f};
    float m_run = -1e30f, l_run = 0.0f;

    const int srow = tid >> 2;
    const int scol = (tid & 3) * 16;
    const bf16_t* khp = Khi + ((size_t)bh * SS + srow) * DD + scol;
    const bf16_t* klp = Klo + ((size_t)bh * SS + srow) * DD + scol;
    const bf16_t* vsp = Vtw + ((size_t)bh * DD + srow) * SS + scol;

    bf16x8 rkh0, rkh1, rkl0, rkl1, rv0, rv1;
    rkh0 = *(const bf16x8*)(khp);     rkh1 = *(const bf16x8*)(khp + 8);
    rkl0 = *(const bf16x8*)(klp);     rkl1 = *(const bf16x8*)(klp + 8);
    rv0  = *(const bf16x8*)(vsp);     rv1  = *(const bf16x8*)(vsp + 8);

    for (int kt = 0; kt < NT; ++kt) {
        __syncthreads();
        *(bf16x8*)&Kh_lds[srow][scol]     = rkh0;
        *(bf16x8*)&Kh_lds[srow][scol + 8] = rkh1;
        *(bf16x8*)&Kl_lds[srow][scol]     = rkl0;
        *(bf16x8*)&Kl_lds[srow][scol + 8] = rkl1;
        *(bf16x8*)&Vt_lds[srow][scol]     = rv0;
        *(bf16x8*)&Vt_lds[srow][scol + 8] = rv1;
        __syncthreads();

        if (kt + 1 < NT) {
            const bf16_t* kh = khp + (size_t)(kt + 1) * 64 * DD;
            const bf16_t* kl = klp + (size_t)(kt + 1) * 64 * DD;
            const bf16_t* vs = vsp + (kt + 1) * 64;
            rkh0 = *(const bf16x8*)(kh);  rkh1 = *(const bf16x8*)(kh + 8);
            rkl0 = *(const bf16x8*)(kl);  rkl1 = *(const bf16x8*)(kl + 8);
            rv0  = *(const bf16x8*)(vs);  rv1  = *(const bf16x8*)(vs + 8);
        }

        f32x4 Sfr[4];
#pragma unroll
        for (int mt = 0; mt < 4; ++mt) {
            f32x4 acc = f32x4{0.f, 0.f, 0.f, 0.f};
#pragma unroll
            for (int kc = 0; kc < 2; ++kc) {
                bf16x8 kh = *(const bf16x8*)&Kh_lds[mt * 16 + l16][kc * 32 + quad * 8];
                bf16x8 kl = *(const bf16x8*)&Kl_lds[mt * 16 + l16][kc * 32 + quad * 8];
                acc = __builtin_amdgcn_mfma_f32_16x16x32_bf16(kh, qhi[kc], acc, 0, 0, 0);
                acc = __builtin_amdgcn_mfma_f32_16x16x32_bf16(kh, qlo[kc], acc, 0, 0, 0);
                acc = __builtin_amdgcn_mfma_f32_16x16x32_bf16(kl, qhi[kc], acc, 0, 0, 0);
            }
            Sfr[mt] = acc;
        }

        float mx = Sfr[0][0];
#pragma unroll
        for (int mt = 0; mt < 4; ++mt)
#pragma unroll
            for (int r = 0; r < 4; ++r) mx = fmaxf(mx, Sfr[mt][r]);
        mx = fmaxf(mx, __shfl_xor(mx, 16));
        mx = fmaxf(mx, __shfl_xor(mx, 32));

        if (__any(mx > m_run)) {
            const float mnew  = fmaxf(m_run, mx);
            const float alpha = exp2f(m_run - mnew);
            m_run = mnew;
            l_run *= alpha;
#pragma unroll
            for (int mt = 0; mt < 4; ++mt) Ot[mt] *= alpha;
        }

        float ps[4][4];
        float rs = 0.0f;
#pragma unroll
        for (int mt = 0; mt < 4; ++mt)
#pragma unroll
            for (int r = 0; r < 4; ++r) {
                ps[mt][r] = exp2f(Sfr[mt][r] - m_run);
                rs += ps[mt][r];
            }
        rs += __shfl_xor(rs, 16);
        rs += __shfl_xor(rs, 32);
        l_run += rs;

#pragma unroll
        for (int mt = 0; mt < 4; ++mt) {
            uint2 w = make_uint2(pack2f(ps[mt][0], ps[mt][1]),
                                 pack2f(ps[mt][2], ps[mt][3]));
            *(uint2*)&Pt_lds[wave][l16][mt * 16 + quad * 4] = w;
        }

#pragma unroll
        for (int kc = 0; kc < 2; ++kc) {
            bf16x8 pf = *(const bf16x8*)&Pt_lds[wave][l16][kc * 32 + quad * 8];
#pragma unroll
            for (int mt = 0; mt < 4; ++mt) {
                bf16x8 vf = *(const bf16x8*)&Vt_lds[mt * 16 + l16][kc * 32 + quad * 8];
                Ot[mt] = __builtin_amdgcn_mfma_f32_16x16x32_bf16(vf, pf, Ot[mt], 0, 0, 0);
            }
        }
    }

    const float inv = 1.0f / l_run;
    float* op = Og + base + (size_t)(q0 + l16) * DD + quad * 4;
#pragma unroll
    for (int mt = 0; mt < 4; ++mt) {
#pragma unroll
        for (int r = 0; r < 4; ++r)
            op[mt * 16 + r] = Ot[mt][r] * inv;
    }
}

// ================= Fallback path B: no-workspace single kernel (R3) =================
__global__ __launch_bounds__(256)
void fattn_fb(const float* __restrict__ Qg, const float* __restrict__ Kg,
              const float* __restrict__ Vg, const float* __restrict__ Mg,
              const float* __restrict__ Sg, float* __restrict__ Og)
{
    __shared__ __align__(16) bf16_t Khi_lds[64][72];
    __shared__ __align__(16) bf16_t Klo_lds[64][72];
    __shared__ __align__(16) bf16_t Vt_lds[DD][72];
    __shared__ __align__(16) bf16_t P_lds[4][2 * 16][72];
    __shared__ float mask_lds[64];

    const int bh   = blockIdx.x % BH;
    const int qt   = blockIdx.x / BH;
    const int b    = bh / HH;
    const int tid  = threadIdx.x;
    const int wave = tid >> 6;
    const int lane = tid & 63;
    const int l16  = lane & 15;
    const int quad = lane >> 4;

    const float sc = Sg[b] * 1.44269504088896340736f;
    const size_t base = (size_t)bh * SS * DD;

    bf16x8 qhi[2][2], qlo[2][2];
#pragma unroll
    for (int mt = 0; mt < 2; ++mt) {
        const float* qp = Qg + base + (size_t)(qt * 128 + mt * 64 + wave * 16 + l16) * DD + quad * 8;
#pragma unroll
        for (int kc = 0; kc < 2; ++kc) {
            float4 a  = *(const float4*)(qp + kc * 32);
            float4 b4 = *(const float4*)(qp + kc * 32 + 4);
            bf16x8 fh, fl;
            BfPair p;
            p = split_bf(a.x);  fh[0] = p.hi; fl[0] = p.lo;
            p = split_bf(a.y);  fh[1] = p.hi; fl[1] = p.lo;
            p = split_bf(a.z);  fh[2] = p.hi; fl[2] = p.lo;
            p = split_bf(a.w);  fh[3] = p.hi; fl[3] = p.lo;
            p = split_bf(b4.x); fh[4] = p.hi; fl[4] = p.lo;
            p = split_bf(b4.y); fh[5] = p.hi; fl[5] = p.lo;
            p = split_bf(b4.z); fh[6] = p.hi; fl[6] = p.lo;
            p = split_bf(b4.w); fh[7] = p.hi; fl[7] = p.lo;
            qhi[mt][kc] = fh; qlo[mt][kc] = fl;
        }
    }

    f32x4 Ofr[2][4];
    float m_run[2][4], l_run[2][4];
#pragma unroll
    for (int mt = 0; mt < 2; ++mt)
#pragma unroll
        for (int r = 0; r < 4; ++r) { m_run[mt][r] = -1e30f; l_run[mt][r] = 0.0f; }
#pragma unroll
    for (int mt = 0; mt < 2; ++mt)
#pragma unroll
        for (int nt = 0; nt < 4; ++nt) Ofr[mt][nt] = f32x4{0.f, 0.f, 0.f, 0.f};

    for (int kt = 0; kt < NT; ++kt) {
        __syncthreads();
        {
            const int cr = tid >> 4;
            const int cc = (tid & 15) * 4;
#pragma unroll
            for (int i = 0; i < 4; ++i) {
                const int row = cr + i * 16;
                float4 kx = *(const float4*)(Kg + base + (size_t)(kt * 64 + row) * DD + cc);
                bf16_t* dh = &Khi_lds[row][cc];
                bf16_t* dl = &Klo_lds[row][cc];
                BfPair p;
                p = split_bf(kx.x); dh[0] = p.hi; dl[0] = p.lo;
                p = split_bf(kx.y); dh[1] = p.hi; dl[1] = p.lo;
                p = split_bf(kx.z); dh[2] = p.hi; dl[2] = p.lo;
                p = split_bf(kx.w); dh[3] = p.hi; dl[3] = p.lo;
            }
            const int d  = tid & 63;
            const int k0 = (tid >> 6) * 16;
#pragma unroll
            for (int i = 0; i < 4; ++i) {
                const int kk = k0 + i * 4;
                const float* vp = Vg + base + (size_t)(kt * 64 + kk) * DD + d;
                float v0 = vp[0 * DD], v1 = vp[1 * DD], v2 = vp[2 * DD], v3 = vp[3 * DD];
                bf16_t* dst = &Vt_lds[d][kk];
                dst[0] = f2bf(v0); dst[1] = f2bf(v1);
                dst[2] = f2bf(v2); dst[3] = f2bf(v3);
            }
            if (tid < 64) mask_lds[tid] = Mg[(size_t)b * SS + kt * 64 + tid];
        }
        __syncthreads();

        f32x4 Sfr[2][4];
#pragma unroll
        for (int nt = 0; nt < 4; ++nt) {
            f32x4 acc0 = f32x4{0.f, 0.f, 0.f, 0.f};
            f32x4 acc1 = f32x4{0.f, 0.f, 0.f, 0.f};
#pragma unroll
            for (int kc = 0; kc < 2; ++kc) {
                bf16x8 kh = *(const bf16x8*)&Khi_lds[nt * 16 + l16][kc * 32 + quad * 8];
                bf16x8 kl = *(const bf16x8*)&Klo_lds[nt * 16 + l16][kc * 32 + quad * 8];
                acc0 = __builtin_amdgcn_mfma_f32_16x16x32_bf16(qhi[0][kc], kh, acc0, 0, 0, 0);
                acc0 = __builtin_amdgcn_mfma_f32_16x16x32_bf16(qhi[0][kc], kl, acc0, 0, 0, 0);
                acc0 = __builtin_amdgcn_mfma_f32_16x16x32_bf16(qlo[0][kc], kh, acc0, 0, 0, 0);
                acc1 = __builtin_amdgcn_mfma_f32_16x16x32_bf16(qhi[1][kc], kh, acc1, 0, 0, 0);
                acc1 = __builtin_amdgcn_mfma_f32_16x16x32_bf16(qhi[1][kc], kl, acc1, 0, 0, 0);
                acc1 = __builtin_amdgcn_mfma_f32_16x16x32_bf16(qlo[1][kc], kh, acc1, 0, 0, 0);
            }
            Sfr[0][nt] = acc0;
            Sfr[1][nt] = acc1;
        }

#pragma unroll
        for (int mt = 0; mt < 2; ++mt) {
#pragma unroll
            for (int r = 0; r < 4; ++r) {
                float s0 = Sfr[mt][0][r] * sc, s1 = Sfr[mt][1][r] * sc;
                float s2 = Sfr[mt][2][r] * sc, s3 = Sfr[mt][3][r] * sc;
                float mx = fmaxf(fmaxf(s0, s1), fmaxf(s2, s3));
                mx = fmaxf(mx, __shfl_xor(mx, 1));
                mx = fmaxf(mx, __shfl_xor(mx, 2));
                mx = fmaxf(mx, __shfl_xor(mx, 4));
                mx = fmaxf(mx, __shfl_xor(mx, 8));
                const float mnew  = fmaxf(m_run[mt][r], mx);
                const float alpha = exp2f(m_run[mt][r] - mnew);
                m_run[mt][r] = mnew;
                float p0 = exp2f(s0 - mnew), p1 = exp2f(s1 - mnew);
                float p2 = exp2f(s2 - mnew), p3 = exp2f(s3 - mnew);
                float rsum = (p0 + p1) + (p2 + p3);
                rsum += __shfl_xor(rsum, 1);
                rsum += __shfl_xor(rsum, 2);
                rsum += __shfl_xor(rsum, 4);
                rsum += __shfl_xor(rsum, 8);
                l_run[mt][r] = l_run[mt][r] * alpha + rsum;
                Ofr[mt][0][r] *= alpha; Ofr[mt][1][r] *= alpha;
                Ofr[mt][2][r] *= alpha; Ofr[mt][3][r] *= alpha;
                const int prow = mt * 16 + quad * 4 + r;
                P_lds[wave][prow][0 * 16 + l16] = f2bf(p0 * mask_lds[0 * 16 + l16]);
                P_lds[wave][prow][1 * 16 + l16] = f2bf(p1 * mask_lds[1 * 16 + l16]);
                P_lds[wave][prow][2 * 16 + l16] = f2bf(p2 * mask_lds[2 * 16 + l16]);
                P_lds[wave][prow][3 * 16 + l16] = f2bf(p3 * mask_lds[3 * 16 + l16]);
            }
        }

#pragma unroll
        for (int kc = 0; kc < 2; ++kc) {
            bf16x8 pf0 = *(const bf16x8*)&P_lds[wave][0 * 16 + l16][kc * 32 + quad * 8];
            bf16x8 pf1 = *(const bf16x8*)&P_lds[wave][1 * 16 + l16][kc * 32 + quad * 8];
#pragma unroll
            for (int nt = 0; nt < 4; ++nt) {
                bf16x8 vf = *(const bf16x8*)&Vt_lds[nt * 16 + l16][kc * 32 + quad * 8];
                Ofr[0][nt] = __builtin_amdgcn_mfma_f32_16x16x32_bf16(pf0, vf, Ofr[0][nt], 0, 0, 0);
                Ofr[1][nt] = __builtin_amdgcn_mfma_f32_16x16x32_bf16(pf1, vf, Ofr[1][nt], 0, 0, 0);
            }
        }
    }

#pragma unroll
    for (int mt = 0; mt < 2; ++mt) {
#pragma unroll
        for (int r = 0; r < 4; ++r) {
            const float inv = 1.0f / l_run[mt][r];
            const size_t row = (size_t)(qt * 128 + mt * 64 + wave * 16 + quad * 4 + r);
            float* op = Og + base + row * DD + l16;
            op[0]  = Ofr[mt][0][r] * inv;
            op[16] = Ofr[mt][1][r] * inv;
            op[32] = Ofr[mt][2][r] * inv;
            op[48] = Ofr[mt][3][r] * inv;
        }
    }
}

extern "C" void kernel_launch(void* const* d_in, const int* in_sizes, int n_in,
                              void* d_out, int out_size, void* d_ws, size_t ws_size,
                              hipStream_t stream) {
    const float* Qg = (const float*)d_in[0];
    const float* Kg = (const float*)d_in[1];
    const float* Vg = (const float*)d_in[2];
    const float* Mg = (const float*)d_in[4];  // key_mask [B,1,1,S]
    const float* Sg = (const float*)d_in[5];  // scale_factor [B,1,1,1]
    float* Og = (float*)d_out;

    if (ws_size >= WS_FUSED) {
        bf16_t* Khi = (bf16_t*)d_ws;
        bf16_t* Klo = Khi + WS_K;
        bf16_t* Vtw = Klo + WS_K;
        uint32_t* flags = (uint32_t*)(Vtw + WS_K);
        fattn_fused<<<dim3(BH * NT), dim3(256), 0, stream>>>(
            Qg, Kg, Vg, Mg, Sg, Og, Khi, Klo, Vtw, flags);
    } else if (ws_size >= WS_NEED) {
        bf16_t* Khi = (bf16_t*)d_ws;
        bf16_t* Klo = Khi + WS_K;
        bf16_t* Vtw = Klo + WS_K;
        conv_kv<<<dim3(BH * NT), dim3(256), 0, stream>>>(Kg, Vg, Mg, Khi, Klo, Vtw);
        fattn3<<<dim3(BH * NT), dim3(256), 0, stream>>>(Qg, Khi, Klo, Vtw, Sg, Og);
    } else {
        fattn_fb<<<dim3(BH * (SS / 128)), dim3(256), 0, stream>>>(Qg, Kg, Vg, Mg, Sg, Og);
    }
}

// Round 9
// 176.171 us; speedup vs baseline: 2.6763x; 2.6763x over previous
//
#include <hip/hip_runtime.h>
#include <hip/hip_bf16.h>
#include <stdint.h>

// Problem constants: B=2, H=16, S=2048, D=64, fp32 in/out.
#define BB 2
#define HH 16
#define SS 2048
#define DD 64
constexpr int BH = BB * HH;
constexpr int NT = SS / 64;    // 32 K-tiles

typedef __bf16 bf16_t;
typedef bf16_t bf16x8 __attribute__((ext_vector_type(8)));
typedef _Float16 f16_t;
typedef f16_t f16x8 __attribute__((ext_vector_type(8)));
typedef float f32x4 __attribute__((ext_vector_type(4)));

// Workspace (f16): Kf[BH][SS][DD] | Vt[BH][DD][SS] (mask folded)
constexpr size_t WS_K      = (size_t)BH * SS * DD;   // 4,194,304 elems
constexpr size_t WS_NEED16 = WS_K * 2 * 2;           // 16,777,216 bytes

__device__ __forceinline__ bf16_t f2bf(float f) {
    uint32_t u = __float_as_uint(f);
    u += 0x7FFFu + ((u >> 16) & 1u);
    return __builtin_bit_cast(bf16_t, (uint16_t)(u >> 16));
}
__device__ __forceinline__ float bf2f(bf16_t h) {
    uint32_t u = ((uint32_t)__builtin_bit_cast(uint16_t, h)) << 16;
    return __uint_as_float(u);
}
struct BfPair { bf16_t hi, lo; };
__device__ __forceinline__ BfPair split_bf(float f) {
    BfPair p;
    p.hi = f2bf(f);
    p.lo = f2bf(f - bf2f(p.hi));
    return p;
}
__device__ __forceinline__ uint32_t pkf16(float a, float b) {
    // two fp32 -> packed f16x2 (v_cvt_pkrtz_f16_f32), as raw dword
    return __builtin_bit_cast(uint32_t, __builtin_amdgcn_cvt_pkrtz(a, b));
}

// ---------- Prologue: K -> f16; V -> Vt f16 transposed + mask folded ----------
// V transpose goes through fp32 LDS with stride 65 (bank-conflict-free column
// reads: addr%32 spans all banks exactly 2x per wave -> free per m136).
__global__ __launch_bounds__(256)
void conv_kv(const float* __restrict__ K, const float* __restrict__ V,
             const float* __restrict__ Mg,
             f16_t* __restrict__ Kf, f16_t* __restrict__ Vt) {
    __shared__ float V_l[64][65];
    __shared__ float msk[64];
    const int bh = blockIdx.x % BH;
    const int kb = blockIdx.x / BH;
    const int b  = bh / HH;
    const int k0 = kb * 64;
    const int tid = threadIdx.x;

    // ---- K convert: thread handles row=tid>>2, cols (tid&3)*16..+15 ----
    {
        const int row = tid >> 2, c16 = (tid & 3) * 16;
        const size_t off = ((size_t)bh * SS + k0 + row) * DD + c16;
        const float* kp = K + off;
        f16x8 h0, h1;
#pragma unroll
        for (int j = 0; j < 8; ++j) h0[j] = (f16_t)kp[j];
#pragma unroll
        for (int j = 0; j < 8; ++j) h1[j] = (f16_t)kp[8 + j];
        *(f16x8*)(Kf + off)     = h0;
        *(f16x8*)(Kf + off + 8) = h1;
    }
    // ---- V tile -> LDS (coalesced float4, row-major) ----
    {
        const int vr = tid >> 4, c4 = (tid & 15) * 4;
#pragma unroll
        for (int i = 0; i < 4; ++i) {
            const int key = vr + i * 16;
            float4 v = *(const float4*)(V + ((size_t)bh * SS + k0 + key) * DD + c4);
            V_l[key][c4 + 0] = v.x; V_l[key][c4 + 1] = v.y;
            V_l[key][c4 + 2] = v.z; V_l[key][c4 + 3] = v.w;
        }
        if (tid < 64) msk[tid] = Mg[(size_t)b * SS + k0 + tid];
    }
    __syncthreads();
    // ---- Transposed read (conflict-free), mask fold, f16 store ----
    {
        const int d = tid >> 2, kc = (tid & 3) * 16;
        f16x8 h0, h1;
#pragma unroll
        for (int j = 0; j < 8; ++j) h0[j] = (f16_t)(V_l[kc + j][d] * msk[kc + j]);
#pragma unroll
        for (int j = 0; j < 8; ++j) h1[j] = (f16_t)(V_l[kc + 8 + j][d] * msk[kc + 8 + j]);
        f16_t* dst = Vt + ((size_t)bh * DD + d) * SS + k0 + kc;
        *(f16x8*)(dst)     = h0;
        *(f16x8*)(dst + 8) = h1;
    }
}

// ---------- Main: transposed-S flash attention, fp16 single (QT=64, 1024 blocks) ----------
// S^T = K·Q^T => lane's 16 S values all belong to q = l16 (in-lane softmax).
// O^T = V^T·P^T; all operand frags contiguous LDS rows.
__global__ __launch_bounds__(256)
void fattn4(const float* __restrict__ Qg, const f16_t* __restrict__ Kf,
            const f16_t* __restrict__ Vtw, const float* __restrict__ Sg,
            float* __restrict__ Og)
{
    __shared__ __align__(16) f16_t Kh_lds[64][72];
    __shared__ __align__(16) f16_t Vt_lds[DD][72];
    __shared__ __align__(16) f16_t Pt_lds[4][16][72];

    const int bh   = blockIdx.x % BH;      // bh-minor => XCD affinity
    const int qt   = blockIdx.x / BH;      // 0..31
    const int b    = bh / HH;
    const int tid  = threadIdx.x;
    const int wave = tid >> 6;
    const int lane = tid & 63;
    const int l16  = lane & 15;
    const int quad = lane >> 4;

    const float sc = Sg[b] * 1.44269504088896340736f;  // scale*log2e, folded into Q
    const size_t base = (size_t)bh * SS * DD;
    const int q0 = qt * 64 + wave * 16;

    // Q fragments (B-operand layout), fp16 of (q * sc)
    f16x8 qf[2];
    {
        const float* qp = Qg + base + (size_t)(q0 + l16) * DD + quad * 8;
#pragma unroll
        for (int kc = 0; kc < 2; ++kc) {
            float4 a  = *(const float4*)(qp + kc * 32);
            float4 b4 = *(const float4*)(qp + kc * 32 + 4);
            f16x8 f;
            f[0] = (f16_t)(a.x * sc);  f[1] = (f16_t)(a.y * sc);
            f[2] = (f16_t)(a.z * sc);  f[3] = (f16_t)(a.w * sc);
            f[4] = (f16_t)(b4.x * sc); f[5] = (f16_t)(b4.y * sc);
            f[6] = (f16_t)(b4.z * sc); f[7] = (f16_t)(b4.w * sc);
            qf[kc] = f;
        }
    }

    f32x4 Ot[4];                // O^T: D[m=d=mt*16+quad*4+r][n=q=l16]
#pragma unroll
    for (int mt = 0; mt < 4; ++mt) Ot[mt] = f32x4{0.f, 0.f, 0.f, 0.f};
    float m_run = -1e30f, l_run = 0.0f;

    const int srow = tid >> 2;             // 0..63
    const int scol = (tid & 3) * 16;
    const f16_t* kfp = Kf  + ((size_t)bh * SS + srow) * DD + scol;
    const f16_t* vsp = Vtw + ((size_t)bh * DD + srow) * SS + scol;

    // Software pipeline: preload tile kt into regs; ds_write at loop head.
    f16x8 rk0, rk1, rv0, rv1;
    rk0 = *(const f16x8*)(kfp);  rk1 = *(const f16x8*)(kfp + 8);
    rv0 = *(const f16x8*)(vsp);  rv1 = *(const f16x8*)(vsp + 8);

    for (int kt = 0; kt < NT; ++kt) {
        __syncthreads();
        *(f16x8*)&Kh_lds[srow][scol]     = rk0;
        *(f16x8*)&Kh_lds[srow][scol + 8] = rk1;
        *(f16x8*)&Vt_lds[srow][scol]     = rv0;
        *(f16x8*)&Vt_lds[srow][scol + 8] = rv1;
        __syncthreads();

        if (kt + 1 < NT) {
            const f16_t* kf = kfp + (size_t)(kt + 1) * 64 * DD;
            const f16_t* vs = vsp + (kt + 1) * 64;
            rk0 = *(const f16x8*)(kf);  rk1 = *(const f16x8*)(kf + 8);
            rv0 = *(const f16x8*)(vs);  rv1 = *(const f16x8*)(vs + 8);
        }

        // ---- S^T = K Q^T (single fp16 MFMA per kc) ----
        f32x4 Sfr[4];
#pragma unroll
        for (int mt = 0; mt < 4; ++mt) {
            f32x4 acc = f32x4{0.f, 0.f, 0.f, 0.f};
#pragma unroll
            for (int kc = 0; kc < 2; ++kc) {
                f16x8 kh = *(const f16x8*)&Kh_lds[mt * 16 + l16][kc * 32 + quad * 8];
                acc = __builtin_amdgcn_mfma_f32_16x16x32_f16(kh, qf[kc], acc, 0, 0, 0);
            }
            Sfr[mt] = acc;   // D[m=key][n=q=l16], pre-scaled (sc in Q)
        }

        // ---- Online softmax: 16 in-lane values (q = l16) ----
        float mx = Sfr[0][0];
#pragma unroll
        for (int mt = 0; mt < 4; ++mt)
#pragma unroll
            for (int r = 0; r < 4; ++r) mx = fmaxf(mx, Sfr[mt][r]);
        mx = fmaxf(mx, __shfl_xor(mx, 16));
        mx = fmaxf(mx, __shfl_xor(mx, 32));

        if (__any(mx > m_run)) {
            const float mnew  = fmaxf(m_run, mx);
            const float alpha = exp2f(m_run - mnew);
            m_run = mnew;
            l_run *= alpha;
#pragma unroll
            for (int mt = 0; mt < 4; ++mt) Ot[mt] *= alpha;
        }

        float ps[4][4];
        float rs = 0.0f;
#pragma unroll
        for (int mt = 0; mt < 4; ++mt)
#pragma unroll
            for (int r = 0; r < 4; ++r) {
                ps[mt][r] = exp2f(Sfr[mt][r] - m_run);
                rs += ps[mt][r];
            }
        rs += __shfl_xor(rs, 16);
        rs += __shfl_xor(rs, 32);
        l_run += rs;

        // ---- P^T -> LDS: packed f16 pairs, 4x ds_write_b64 ----
#pragma unroll
        for (int mt = 0; mt < 4; ++mt) {
            uint2 w = make_uint2(pkf16(ps[mt][0], ps[mt][1]),
                                 pkf16(ps[mt][2], ps[mt][3]));
            *(uint2*)&Pt_lds[wave][l16][mt * 16 + quad * 4] = w;
        }
        // Pt_lds is per-wave private; in-wave RAW handled by lgkmcnt.

        // ---- O^T += V^T P^T ----
#pragma unroll
        for (int kc = 0; kc < 2; ++kc) {
            f16x8 pf = *(const f16x8*)&Pt_lds[wave][l16][kc * 32 + quad * 8];
#pragma unroll
            for (int mt = 0; mt < 4; ++mt) {
                f16x8 vf = *(const f16x8*)&Vt_lds[mt * 16 + l16][kc * 32 + quad * 8];
                Ot[mt] = __builtin_amdgcn_mfma_f32_16x16x32_f16(vf, pf, Ot[mt], 0, 0, 0);
            }
        }
    }

    // ---- Epilogue: O[q][d] = O^T[d][q] / l ----
    const float inv = 1.0f / l_run;
    float* op = Og + base + (size_t)(q0 + l16) * DD + quad * 4;
#pragma unroll
    for (int mt = 0; mt < 4; ++mt) {
#pragma unroll
        for (int r = 0; r < 4; ++r)
            op[mt * 16 + r] = Ot[mt][r] * inv;
    }
}

// ================= Fallback: no-workspace single kernel (R3, validated) =================
__global__ __launch_bounds__(256)
void fattn_fb(const float* __restrict__ Qg, const float* __restrict__ Kg,
              const float* __restrict__ Vg, const float* __restrict__ Mg,
              const float* __restrict__ Sg, float* __restrict__ Og)
{
    __shared__ __align__(16) bf16_t Khi_lds[64][72];
    __shared__ __align__(16) bf16_t Klo_lds[64][72];
    __shared__ __align__(16) bf16_t Vt_lds[DD][72];
    __shared__ __align__(16) bf16_t P_lds[4][2 * 16][72];
    __shared__ float mask_lds[64];

    const int bh   = blockIdx.x % BH;
    const int qt   = blockIdx.x / BH;
    const int b    = bh / HH;
    const int tid  = threadIdx.x;
    const int wave = tid >> 6;
    const int lane = tid & 63;
    const int l16  = lane & 15;
    const int quad = lane >> 4;

    const float sc = Sg[b] * 1.44269504088896340736f;
    const size_t base = (size_t)bh * SS * DD;

    bf16x8 qhi[2][2], qlo[2][2];
#pragma unroll
    for (int mt = 0; mt < 2; ++mt) {
        const float* qp = Qg + base + (size_t)(qt * 128 + mt * 64 + wave * 16 + l16) * DD + quad * 8;
#pragma unroll
        for (int kc = 0; kc < 2; ++kc) {
            float4 a  = *(const float4*)(qp + kc * 32);
            float4 b4 = *(const float4*)(qp + kc * 32 + 4);
            bf16x8 fh, fl;
            BfPair p;
            p = split_bf(a.x);  fh[0] = p.hi; fl[0] = p.lo;
            p = split_bf(a.y);  fh[1] = p.hi; fl[1] = p.lo;
            p = split_bf(a.z);  fh[2] = p.hi; fl[2] = p.lo;
            p = split_bf(a.w);  fh[3] = p.hi; fl[3] = p.lo;
            p = split_bf(b4.x); fh[4] = p.hi; fl[4] = p.lo;
            p = split_bf(b4.y); fh[5] = p.hi; fl[5] = p.lo;
            p = split_bf(b4.z); fh[6] = p.hi; fl[6] = p.lo;
            p = split_bf(b4.w); fh[7] = p.hi; fl[7] = p.lo;
            qhi[mt][kc] = fh; qlo[mt][kc] = fl;
        }
    }

    f32x4 Ofr[2][4];
    float m_run[2][4], l_run[2][4];
#pragma unroll
    for (int mt = 0; mt < 2; ++mt)
#pragma unroll
        for (int r = 0; r < 4; ++r) { m_run[mt][r] = -1e30f; l_run[mt][r] = 0.0f; }
#pragma unroll
    for (int mt = 0; mt < 2; ++mt)
#pragma unroll
        for (int nt = 0; nt < 4; ++nt) Ofr[mt][nt] = f32x4{0.f, 0.f, 0.f, 0.f};

    for (int kt = 0; kt < NT; ++kt) {
        __syncthreads();
        {
            const int cr = tid >> 4;
            const int cc = (tid & 15) * 4;
#pragma unroll
            for (int i = 0; i < 4; ++i) {
                const int row = cr + i * 16;
                float4 kx = *(const float4*)(Kg + base + (size_t)(kt * 64 + row) * DD + cc);
                bf16_t* dh = &Khi_lds[row][cc];
                bf16_t* dl = &Klo_lds[row][cc];
                BfPair p;
                p = split_bf(kx.x); dh[0] = p.hi; dl[0] = p.lo;
                p = split_bf(kx.y); dh[1] = p.hi; dl[1] = p.lo;
                p = split_bf(kx.z); dh[2] = p.hi; dl[2] = p.lo;
                p = split_bf(kx.w); dh[3] = p.hi; dl[3] = p.lo;
            }
            const int d  = tid & 63;
            const int k0 = (tid >> 6) * 16;
#pragma unroll
            for (int i = 0; i < 4; ++i) {
                const int kk = k0 + i * 4;
                const float* vp = Vg + base + (size_t)(kt * 64 + kk) * DD + d;
                float v0 = vp[0 * DD], v1 = vp[1 * DD], v2 = vp[2 * DD], v3 = vp[3 * DD];
                bf16_t* dst = &Vt_lds[d][kk];
                dst[0] = f2bf(v0); dst[1] = f2bf(v1);
                dst[2] = f2bf(v2); dst[3] = f2bf(v3);
            }
            if (tid < 64) mask_lds[tid] = Mg[(size_t)b * SS + kt * 64 + tid];
        }
        __syncthreads();

        f32x4 Sfr[2][4];
#pragma unroll
        for (int nt = 0; nt < 4; ++nt) {
            f32x4 acc0 = f32x4{0.f, 0.f, 0.f, 0.f};
            f32x4 acc1 = f32x4{0.f, 0.f, 0.f, 0.f};
#pragma unroll
            for (int kc = 0; kc < 2; ++kc) {
                bf16x8 kh = *(const bf16x8*)&Khi_lds[nt * 16 + l16][kc * 32 + quad * 8];
                bf16x8 kl = *(const bf16x8*)&Klo_lds[nt * 16 + l16][kc * 32 + quad * 8];
                acc0 = __builtin_amdgcn_mfma_f32_16x16x32_bf16(qhi[0][kc], kh, acc0, 0, 0, 0);
                acc0 = __builtin_amdgcn_mfma_f32_16x16x32_bf16(qhi[0][kc], kl, acc0, 0, 0, 0);
                acc0 = __builtin_amdgcn_mfma_f32_16x16x32_bf16(qlo[0][kc], kh, acc0, 0, 0, 0);
                acc1 = __builtin_amdgcn_mfma_f32_16x16x32_bf16(qhi[1][kc], kh, acc1, 0, 0, 0);
                acc1 = __builtin_amdgcn_mfma_f32_16x16x32_bf16(qhi[1][kc], kl, acc1, 0, 0, 0);
                acc1 = __builtin_amdgcn_mfma_f32_16x16x32_bf16(qlo[1][kc], kh, acc1, 0, 0, 0);
            }
            Sfr[0][nt] = acc0;
            Sfr[1][nt] = acc1;
        }

#pragma unroll
        for (int mt = 0; mt < 2; ++mt) {
#pragma unroll
            for (int r = 0; r < 4; ++r) {
                float s0 = Sfr[mt][0][r] * sc, s1 = Sfr[mt][1][r] * sc;
                float s2 = Sfr[mt][2][r] * sc, s3 = Sfr[mt][3][r] * sc;
                float mx = fmaxf(fmaxf(s0, s1), fmaxf(s2, s3));
                mx = fmaxf(mx, __shfl_xor(mx, 1));
                mx = fmaxf(mx, __shfl_xor(mx, 2));
                mx = fmaxf(mx, __shfl_xor(mx, 4));
                mx = fmaxf(mx, __shfl_xor(mx, 8));
                const float mnew  = fmaxf(m_run[mt][r], mx);
                const float alpha = exp2f(m_run[mt][r] - mnew);
                m_run[mt][r] = mnew;
                float p0 = exp2f(s0 - mnew), p1 = exp2f(s1 - mnew);
                float p2 = exp2f(s2 - mnew), p3 = exp2f(s3 - mnew);
                float rsum = (p0 + p1) + (p2 + p3);
                rsum += __shfl_xor(rsum, 1);
                rsum += __shfl_xor(rsum, 2);
                rsum += __shfl_xor(rsum, 4);
                rsum += __shfl_xor(rsum, 8);
                l_run[mt][r] = l_run[mt][r] * alpha + rsum;
                Ofr[mt][0][r] *= alpha; Ofr[mt][1][r] *= alpha;
                Ofr[mt][2][r] *= alpha; Ofr[mt][3][r] *= alpha;
                const int prow = mt * 16 + quad * 4 + r;
                P_lds[wave][prow][0 * 16 + l16] = f2bf(p0 * mask_lds[0 * 16 + l16]);
                P_lds[wave][prow][1 * 16 + l16] = f2bf(p1 * mask_lds[1 * 16 + l16]);
                P_lds[wave][prow][2 * 16 + l16] = f2bf(p2 * mask_lds[2 * 16 + l16]);
                P_lds[wave][prow][3 * 16 + l16] = f2bf(p3 * mask_lds[3 * 16 + l16]);
            }
        }

#pragma unroll
        for (int kc = 0; kc < 2; ++kc) {
            bf16x8 pf0 = *(const bf16x8*)&P_lds[wave][0 * 16 + l16][kc * 32 + quad * 8];
            bf16x8 pf1 = *(const bf16x8*)&P_lds[wave][1 * 16 + l16][kc * 32 + quad * 8];
#pragma unroll
            for (int nt = 0; nt < 4; ++nt) {
                bf16x8 vf = *(const bf16x8*)&Vt_lds[nt * 16 + l16][kc * 32 + quad * 8];
                Ofr[0][nt] = __builtin_amdgcn_mfma_f32_16x16x32_bf16(pf0, vf, Ofr[0][nt], 0, 0, 0);
                Ofr[1][nt] = __builtin_amdgcn_mfma_f32_16x16x32_bf16(pf1, vf, Ofr[1][nt], 0, 0, 0);
            }
        }
    }

#pragma unroll
    for (int mt = 0; mt < 2; ++mt) {
#pragma unroll
        for (int r = 0; r < 4; ++r) {
            const float inv = 1.0f / l_run[mt][r];
            const size_t row = (size_t)(qt * 128 + mt * 64 + wave * 16 + quad * 4 + r);
            float* op = Og + base + row * DD + l16;
            op[0]  = Ofr[mt][0][r] * inv;
            op[16] = Ofr[mt][1][r] * inv;
            op[32] = Ofr[mt][2][r] * inv;
            op[48] = Ofr[mt][3][r] * inv;
        }
    }
}

extern "C" void kernel_launch(void* const* d_in, const int* in_sizes, int n_in,
                              void* d_out, int out_size, void* d_ws, size_t ws_size,
                              hipStream_t stream) {
    const float* Qg = (const float*)d_in[0];
    const float* Kg = (const float*)d_in[1];
    const float* Vg = (const float*)d_in[2];
    const float* Mg = (const float*)d_in[4];  // key_mask [B,1,1,S]
    const float* Sg = (const float*)d_in[5];  // scale_factor [B,1,1,1]
    float* Og = (float*)d_out;

    if (ws_size >= WS_NEED16) {
        f16_t* Kf = (f16_t*)d_ws;
        f16_t* Vt = Kf + WS_K;
        conv_kv<<<dim3(BH * NT), dim3(256), 0, stream>>>(Kg, Vg, Mg, Kf, Vt);
        fattn4<<<dim3(BH * NT), dim3(256), 0, stream>>>(Qg, Kf, Vt, Sg, Og);
    } else {
        fattn_fb<<<dim3(BH * (SS / 128)), dim3(256), 0, stream>>>(Qg, Kg, Vg, Mg, Sg, Og);
    }
}